// Round 8
// baseline (440.755 us; speedup 1.0000x reference)
//
#include <hip/hip_runtime.h>
#include <math.h>

#ifndef M_PI
#define M_PI 3.14159265358979323846
#endif

typedef unsigned int u32;

// Problem constants
constexpr int  NB   = 8;
constexpr int  CH   = 256;
constexpr long HW   = 4096;                 // 64*64
constexpr long SLOT = (long)NB * CH * HW;   // elems per [8,256,64,64] tensor
constexpr int  SPLITK = 8;                  // logits GEMM split factor
constexpr long ST   = (long)CH * HW;        // 1048576

// ===========================================================================
// Packed split-bf16 format: u32 = bits(bf16_rne_hi(x)) | bits(bf16_trunc(lo))>>16
//   hi in top 16 bits, lo in low 16 bits; reconstruction error ~2^-17 relative.
// ===========================================================================
__device__ __forceinline__ float rne_hi(float x) {
  unsigned u = __float_as_uint(x);
  unsigned r = (u + 0x7FFFu + ((u >> 16) & 1u)) & 0xFFFF0000u;
  return __uint_as_float(r);
}
__device__ __forceinline__ u32 packf(float x) {
  const float h = rne_hi(x);
  const float l = x - h;
  return (__float_as_uint(h) & 0xFFFF0000u) | (__float_as_uint(l) >> 16);
}
__device__ __forceinline__ float unpackf(u32 u) {
  return __uint_as_float(u & 0xFFFF0000u) + __uint_as_float(u << 16);
}
__device__ __forceinline__ unsigned bfpair(float x, float y) {
  return (__float_as_uint(x) >> 16) | (__float_as_uint(y) & 0xFFFF0000u);
}

typedef short bf16x8 __attribute__((ext_vector_type(8)));
typedef float f32x4  __attribute__((ext_vector_type(4)));

// ===========================================================================
// cvt: fp32 -> packed u32; SIX tensors in ONE launch (blockIdx.y dispatch)
// ===========================================================================
struct CvtJob { const float* src; u32* dst; int n4; };

__global__ __launch_bounds__(256)
void cvt_kernel(CvtJob j0, CvtJob j1, CvtJob j2, CvtJob j3, CvtJob j4, CvtJob j5)
{
  const int yy = blockIdx.y;
  CvtJob j;
  switch (yy) {
    case 0: j = j0; break;
    case 1: j = j1; break;
    case 2: j = j2; break;
    case 3: j = j3; break;
    case 4: j = j4; break;
    default: j = j5; break;
  }
  const int i = blockIdx.x * 256 + threadIdx.x;
  if (i < j.n4) {
    const float4 v = ((const float4*)j.src)[i];
    uint4 o;
    o.x = packf(v.x); o.y = packf(v.y); o.z = packf(v.z); o.w = packf(v.w);
    ((uint4*)j.dst)[i] = o;
  }
}

// ===========================================================================
// MFMA split-bf16 GEMM: C[b](256 x 4096) = A[b](256 x K) * B[b](K x 4096)
// A always packed-u32 [M][K]. B: BPACKED ? packed-u32 [K][N] : fp32 [K][N].
// 3-product emulation: C ~= Ah*Bh + Ah*Bl + Al*Bh.
// v8: PAD-FREE LDS via XOR chunk-swizzle. Row = 32 shorts (one BK=32 k-tile),
// 16B chunk c of row r lives at SWZ(r,c) = r*32 + ((c^(r&3))<<3). Same
// (row,chunk)->data mapping as the padded layout -> bitwise-identical MFMA
// inputs. LDS 72KB -> 48KB -> 3 blocks/CU (was 2): r7 counters showed
// Occ 18.6%, all pipes <=27% -> latency-bound, occupancy is the lever
// (pad only bought 6%-of-cycles bank conflicts). Bank check: per quad-group
// reads hit 8 distinct 16B starts -> 2 lanes/bank = free (m136).
// v7 multi-problem blockIdx.y dispatch kept (QKV: same-B L2 sharing, FETCH
// 221->29.8MB measured).
// Block tile 256x128 (full M), 512 threads = 8 waves (4m x 2n).
// EPI 0: fp32 +bias store (final). EPI 1: packed +bias store.
// EPI 2: mix = beta*(cfr*(Q-lam*V)+V)+(1-beta)*Fw -> packed store.
// ===========================================================================
struct GemmSet {
  const u32*   A;        // packed weights / logits
  const void*  B;        // activation
  void*        C;        // output
  const float* bias;     // nullable
  int          K;
  long         bStride;  // B batch stride (elements)
};

#define SWZ(row, chunk) (((row) << 5) + ((((chunk) ^ ((row) & 3))) << 3))

template<bool BPACKED, int EPI>
__global__ __launch_bounds__(512, 2)
void gemm_mfma(GemmSet g0, GemmSet g1, GemmSet g2,
               long aStride, long cStride,
               const u32* __restrict__ qb, const u32* __restrict__ vb,
               const u32* __restrict__ fwb,
               const float* __restrict__ lambd, const float* __restrict__ beta)
{
  constexpr int N = 4096;
  __shared__ __align__(16) unsigned short sAh[256 * 32];
  __shared__ __align__(16) unsigned short sAl[256 * 32];
  __shared__ __align__(16) unsigned short sBh[128 * 32];
  __shared__ __align__(16) unsigned short sBl[128 * 32];

  const int tid = threadIdx.x;
  const int b   = blockIdx.z;
  const int yy  = blockIdx.y;
  const int n0  = blockIdx.x * 128;

  const GemmSet g = (yy == 0) ? g0 : ((yy == 1) ? g1 : g2);
  const u32*   A       = g.A;
  const void*  Bv      = g.B;
  void*        Cv      = g.C;
  const float* bias    = g.bias;
  const int    K       = g.K;
  const long   bStride = g.bStride;

  const u32* Ab = A + (long)b * aStride;

  const int ar = tid >> 1;            // 0..255 (full M rows)
  const int ak = (tid & 1) * 16;      // k-offset (shorts) for global load
  const int ac0 = (tid & 1) * 2;      // first 16B chunk this thread commits
  const int bn = tid & 127;           // 0..127 (n within tile)
  const int bc0 = tid >> 7;           // 0..3: B chunk; bk = bc0*8
  const int bk = bc0 * 8;

  const int wv = tid >> 6, lane = tid & 63;
  const int wy = wv >> 1, wx = wv & 1;   // wy 0..3 (m), wx 0..1 (n)
  const int quad = lane >> 4, l15 = lane & 15;

  f32x4 acc[4][4];
#pragma unroll
  for (int i = 0; i < 4; ++i)
#pragma unroll
    for (int j = 0; j < 4; ++j) acc[i][j] = (f32x4){0.f, 0.f, 0.f, 0.f};

  u32   ra[16];
  u32   rbu[8];
  float rbf[8];
  {
    const u32* ap = Ab + (long)ar * K + ak;
#pragma unroll
    for (int i = 0; i < 4; ++i) {
      const uint4 t = *(const uint4*)(ap + i * 4);
      ra[4*i] = t.x; ra[4*i+1] = t.y; ra[4*i+2] = t.z; ra[4*i+3] = t.w;
    }
    if (BPACKED) {
      const u32* bp = (const u32*)Bv + (long)b * bStride + (long)bk * N + n0 + bn;
#pragma unroll
      for (int i = 0; i < 8; ++i) rbu[i] = bp[(long)i * N];
    } else {
      const float* bp = (const float*)Bv + (long)b * bStride + (long)bk * N + n0 + bn;
#pragma unroll
      for (int i = 0; i < 8; ++i) rbf[i] = bp[(long)i * N];
    }
  }

  for (int kt = 0; kt < K; kt += 32) {
    // commit A (packed split: 4 ops / 2 elems); chunks ac0, ac0+1 swizzled
    {
      u32 hi[8], lo[8];
#pragma unroll
      for (int e = 0; e < 8; ++e) {
        const u32 u0 = ra[2*e], u1 = ra[2*e+1];
        hi[e] = (u0 >> 16) | (u1 & 0xFFFF0000u);
        lo[e] = (u0 & 0xFFFFu) | (u1 << 16);
      }
      *(uint4*)&sAh[SWZ(ar, ac0)]     = make_uint4(hi[0], hi[1], hi[2], hi[3]);
      *(uint4*)&sAh[SWZ(ar, ac0 + 1)] = make_uint4(hi[4], hi[5], hi[6], hi[7]);
      *(uint4*)&sAl[SWZ(ar, ac0)]     = make_uint4(lo[0], lo[1], lo[2], lo[3]);
      *(uint4*)&sAl[SWZ(ar, ac0 + 1)] = make_uint4(lo[4], lo[5], lo[6], lo[7]);
    }
    // commit B (8 k-values per thread -> 1 chunk per plane, swizzled)
    if (BPACKED) {
      u32 hi[4], lo[4];
#pragma unroll
      for (int e = 0; e < 4; ++e) {
        const u32 u0 = rbu[2*e], u1 = rbu[2*e+1];
        hi[e] = (u0 >> 16) | (u1 & 0xFFFF0000u);
        lo[e] = (u0 & 0xFFFFu) | (u1 << 16);
      }
      *(uint4*)&sBh[SWZ(bn, bc0)] = make_uint4(hi[0], hi[1], hi[2], hi[3]);
      *(uint4*)&sBl[SWZ(bn, bc0)] = make_uint4(lo[0], lo[1], lo[2], lo[3]);
    } else {
      float h[8], l[8];
#pragma unroll
      for (int e = 0; e < 8; ++e) { h[e] = rne_hi(rbf[e]); l[e] = rbf[e] - h[e]; }
      *(uint4*)&sBh[SWZ(bn, bc0)] = make_uint4(bfpair(h[0],h[1]), bfpair(h[2],h[3]),
                                               bfpair(h[4],h[5]), bfpair(h[6],h[7]));
      *(uint4*)&sBl[SWZ(bn, bc0)] = make_uint4(bfpair(l[0],l[1]), bfpair(l[2],l[3]),
                                               bfpair(l[4],l[5]), bfpair(l[6],l[7]));
    }
    __syncthreads();

    // prefetch next tile
    if (kt + 32 < K) {
      const u32* ap = Ab + (long)ar * K + kt + 32 + ak;
#pragma unroll
      for (int i = 0; i < 4; ++i) {
        const uint4 t = *(const uint4*)(ap + i * 4);
        ra[4*i] = t.x; ra[4*i+1] = t.y; ra[4*i+2] = t.z; ra[4*i+3] = t.w;
      }
      if (BPACKED) {
        const u32* bp = (const u32*)Bv + (long)b * bStride + (long)(kt + 32 + bk) * N + n0 + bn;
#pragma unroll
        for (int i = 0; i < 8; ++i) rbu[i] = bp[(long)i * N];
      } else {
        const float* bp = (const float*)Bv + (long)b * bStride + (long)(kt + 32 + bk) * N + n0 + bn;
#pragma unroll
        for (int i = 0; i < 8; ++i) rbf[i] = bp[(long)i * N];
      }
    }

    // fragments + 48 MFMA (chunk = quad, swizzled)
    bf16x8 ah[4], al[4];
#pragma unroll
    for (int i = 0; i < 4; ++i) {
      const int rowa = wy * 64 + i * 16 + l15;
      ah[i] = *(const bf16x8*)&sAh[SWZ(rowa, quad)];
      al[i] = *(const bf16x8*)&sAl[SWZ(rowa, quad)];
    }
#pragma unroll
    for (int j = 0; j < 4; ++j) {
      const int rowb = wx * 64 + j * 16 + l15;
      const bf16x8 bh = *(const bf16x8*)&sBh[SWZ(rowb, quad)];
      const bf16x8 bl = *(const bf16x8*)&sBl[SWZ(rowb, quad)];
#pragma unroll
      for (int i = 0; i < 4; ++i) {
        acc[i][j] = __builtin_amdgcn_mfma_f32_16x16x32_bf16(ah[i], bh, acc[i][j], 0, 0, 0);
        acc[i][j] = __builtin_amdgcn_mfma_f32_16x16x32_bf16(ah[i], bl, acc[i][j], 0, 0, 0);
        acc[i][j] = __builtin_amdgcn_mfma_f32_16x16x32_bf16(al[i], bh, acc[i][j], 0, 0, 0);
      }
    }
    __syncthreads();
  }

  // epilogue
  if (EPI == 0) {
    float* Cb = (float*)Cv + (long)b * cStride;
#pragma unroll
    for (int i = 0; i < 4; ++i)
#pragma unroll
      for (int r = 0; r < 4; ++r) {
        const int row = wy * 64 + i * 16 + quad * 4 + r;
        const float bb = bias ? bias[row] : 0.f;
#pragma unroll
        for (int j = 0; j < 4; ++j) {
          const int col = n0 + wx * 64 + j * 16 + l15;
          Cb[(long)row * N + col] = acc[i][j][r] + bb;
        }
      }
  } else if (EPI == 1) {
    u32* Cb = (u32*)Cv + (long)b * cStride;
#pragma unroll
    for (int i = 0; i < 4; ++i)
#pragma unroll
      for (int r = 0; r < 4; ++r) {
        const int row = wy * 64 + i * 16 + quad * 4 + r;
        const float bb = bias ? bias[row] : 0.f;
#pragma unroll
        for (int j = 0; j < 4; ++j) {
          const int col = n0 + wx * 64 + j * 16 + l15;
          Cb[(long)row * N + col] = packf(acc[i][j][r] + bb);
        }
      }
  } else {
    u32* Cb = (u32*)Cv + (long)b * cStride;
    const float lam = lambd[0], bet = beta[0];
#pragma unroll
    for (int i = 0; i < 4; ++i)
#pragma unroll
      for (int r = 0; r < 4; ++r) {
        const int row = wy * 64 + i * 16 + quad * 4 + r;
#pragma unroll
        for (int j = 0; j < 4; ++j) {
          const int col = n0 + wx * 64 + j * 16 + l15;
          const long off = (long)row * N + col;
          const long gi  = (long)b * cStride + off;
          const float q = unpackf(qb[gi]);
          const float v = unpackf(vb[gi]);
          const float f = unpackf(fwb[gi]);
          Cb[off] = packf(bet * (acc[i][j][r] * (q - lam * v) + v) + (1.f - bet) * f);
        }
      }
  }
}

// ===========================================================================
// MFMA logits GEMM: Lp[b,s](256x256) = Q[b](256x4096) . Krev[b]^T over k-span s
// Both operands packed-u32, K-contiguous. Tile 128x128, split-K=8, BK=32.
// ===========================================================================
__global__ __launch_bounds__(256)
void gemm_logits(const u32* __restrict__ Q, const u32* __restrict__ Kr,
                 float* __restrict__ Lp)
{
  __shared__ __align__(16) unsigned short sAh[128 * 48];
  __shared__ __align__(16) unsigned short sAl[128 * 48];
  __shared__ __align__(16) unsigned short sBh[128 * 48];
  __shared__ __align__(16) unsigned short sBl[128 * 48];

  const int tid = threadIdx.x;
  const int bz  = blockIdx.z;            // b*8 + s
  const int b   = bz >> 3, sp = bz & 7;
  const int m0  = blockIdx.y * 128;
  const int n0  = blockIdx.x * 128;
  const long k0b = (long)sp * 512;

  const int ar = tid >> 1;
  const int ak = (tid & 1) * 16;
  const int aBase = ar * 48 + ak;

  const int wv = tid >> 6, lane = tid & 63;
  const int wy = wv >> 1, wx = wv & 1;
  const int quad = lane >> 4, l15 = lane & 15;

  f32x4 acc[4][4];
#pragma unroll
  for (int i = 0; i < 4; ++i)
#pragma unroll
    for (int j = 0; j < 4; ++j) acc[i][j] = (f32x4){0.f, 0.f, 0.f, 0.f};

  const u32* Abase = Q  + (long)b * ST + (long)(m0 + ar) * 4096 + k0b + ak;
  const u32* Bbase = Kr + (long)b * ST + (long)(n0 + ar) * 4096 + k0b + ak;

  u32 ra[16], rb[16];
#pragma unroll
  for (int i = 0; i < 4; ++i) {
    uint4 t = *(const uint4*)(Abase + i * 4);
    ra[4*i] = t.x; ra[4*i+1] = t.y; ra[4*i+2] = t.z; ra[4*i+3] = t.w;
    t = *(const uint4*)(Bbase + i * 4);
    rb[4*i] = t.x; rb[4*i+1] = t.y; rb[4*i+2] = t.z; rb[4*i+3] = t.w;
  }

  for (int kt = 0; kt < 512; kt += 32) {
    {
      u32 hi[8], lo[8];
#pragma unroll
      for (int e = 0; e < 8; ++e) {
        const u32 u0 = ra[2*e], u1 = ra[2*e+1];
        hi[e] = (u0 >> 16) | (u1 & 0xFFFF0000u);
        lo[e] = (u0 & 0xFFFFu) | (u1 << 16);
      }
      *(uint4*)&sAh[aBase]     = make_uint4(hi[0], hi[1], hi[2], hi[3]);
      *(uint4*)&sAh[aBase + 8] = make_uint4(hi[4], hi[5], hi[6], hi[7]);
      *(uint4*)&sAl[aBase]     = make_uint4(lo[0], lo[1], lo[2], lo[3]);
      *(uint4*)&sAl[aBase + 8] = make_uint4(lo[4], lo[5], lo[6], lo[7]);
#pragma unroll
      for (int e = 0; e < 8; ++e) {
        const u32 u0 = rb[2*e], u1 = rb[2*e+1];
        hi[e] = (u0 >> 16) | (u1 & 0xFFFF0000u);
        lo[e] = (u0 & 0xFFFFu) | (u1 << 16);
      }
      *(uint4*)&sBh[aBase]     = make_uint4(hi[0], hi[1], hi[2], hi[3]);
      *(uint4*)&sBh[aBase + 8] = make_uint4(hi[4], hi[5], hi[6], hi[7]);
      *(uint4*)&sBl[aBase]     = make_uint4(lo[0], lo[1], lo[2], lo[3]);
      *(uint4*)&sBl[aBase + 8] = make_uint4(lo[4], lo[5], lo[6], lo[7]);
    }
    __syncthreads();

    if (kt + 32 < 512) {
#pragma unroll
      for (int i = 0; i < 4; ++i) {
        uint4 t = *(const uint4*)(Abase + kt + 32 + i * 4);
        ra[4*i] = t.x; ra[4*i+1] = t.y; ra[4*i+2] = t.z; ra[4*i+3] = t.w;
        t = *(const uint4*)(Bbase + kt + 32 + i * 4);
        rb[4*i] = t.x; rb[4*i+1] = t.y; rb[4*i+2] = t.z; rb[4*i+3] = t.w;
      }
    }

    bf16x8 ah[4], al[4];
#pragma unroll
    for (int i = 0; i < 4; ++i) {
      const int idx = (wy * 64 + i * 16 + l15) * 48 + quad * 8;
      ah[i] = *(const bf16x8*)&sAh[idx];
      al[i] = *(const bf16x8*)&sAl[idx];
    }
#pragma unroll
    for (int j = 0; j < 4; ++j) {
      const int idx = (wx * 64 + j * 16 + l15) * 48 + quad * 8;
      const bf16x8 bh = *(const bf16x8*)&sBh[idx];
      const bf16x8 bl = *(const bf16x8*)&sBl[idx];
#pragma unroll
      for (int i = 0; i < 4; ++i) {
        acc[i][j] = __builtin_amdgcn_mfma_f32_16x16x32_bf16(ah[i], bh, acc[i][j], 0, 0, 0);
        acc[i][j] = __builtin_amdgcn_mfma_f32_16x16x32_bf16(ah[i], bl, acc[i][j], 0, 0, 0);
        acc[i][j] = __builtin_amdgcn_mfma_f32_16x16x32_bf16(al[i], bh, acc[i][j], 0, 0, 0);
      }
    }
    __syncthreads();
  }

  float* Lb = Lp + (long)bz * 65536;
#pragma unroll
  for (int i = 0; i < 4; ++i)
#pragma unroll
    for (int r = 0; r < 4; ++r) {
      const int row = m0 + wy * 64 + i * 16 + quad * 4 + r;
#pragma unroll
      for (int j = 0; j < 4; ++j) {
        const int col = n0 + wx * 64 + j * 16 + l15;
        Lb[(long)row * 256 + col] = acc[i][j][r];
      }
    }
}

// ---------------------------------------------------------------------------
// pooled[b,c] = mean over HW of (FR + FN)   (packed inputs)
// ---------------------------------------------------------------------------
__global__ __launch_bounds__(256)
void pool_kernel(const u32* __restrict__ FR, const u32* __restrict__ FN,
                 float* __restrict__ pooled)
{
  __shared__ float red[256];
  const int bc = blockIdx.x, tid = threadIdx.x;
  const uint4* a = (const uint4*)(FR + (long)bc * HW);
  const uint4* b = (const uint4*)(FN + (long)bc * HW);
  float s = 0.f;
  for (int v = tid; v < 1024; v += 256) {
    const uint4 x = a[v];
    s += unpackf(x.x) + unpackf(x.y) + unpackf(x.z) + unpackf(x.w);
    const uint4 y = b[v];
    s += unpackf(y.x) + unpackf(y.y) + unpackf(y.z) + unpackf(y.w);
  }
  red[tid] = s; __syncthreads();
  for (int o = 128; o > 0; o >>= 1) {
    if (tid < o) red[tid] += red[tid + o];
    __syncthreads();
  }
  if (tid == 0) pooled[bc] = red[0] * (1.f / 4096.f);
}

// ---------------------------------------------------------------------------
// MLP (relu) + 2-way softmax -> attn2 [8,2,256]  (fp32 throughout)
// ---------------------------------------------------------------------------
__global__ __launch_bounds__(256)
void attn2_kernel(const float* __restrict__ pooled, const float* __restrict__ w1,
                  const float* __restrict__ w2, float* __restrict__ attn2)
{
  __shared__ float ps[256];
  __shared__ float hs[32];
  const int b = blockIdx.x, tid = threadIdx.x;
  ps[tid] = pooled[b * 256 + tid];
  __syncthreads();
  if (tid < 32) {
    float a = 0.f;
    for (int c = 0; c < 256; ++c) a += ps[c] * w1[tid * 256 + c];
    hs[tid] = fmaxf(a, 0.f);
  }
  __syncthreads();
  float a0 = 0.f, a1 = 0.f;
  for (int d = 0; d < 32; ++d) {
    const float h = hs[d];
    a0 += h * w2[tid * 32 + d];
    a1 += h * w2[(256 + tid) * 32 + d];
  }
  const float m  = fmaxf(a0, a1);
  const float e0 = expf(a0 - m), e1 = expf(a1 - m);
  const float inv = 1.f / (e0 + e1);
  attn2[b * 512 + tid]       = e0 * inv;
  attn2[b * 512 + 256 + tid] = e1 * inv;
}

// ---------------------------------------------------------------------------
// Fw = a0*FR + a1*FN   (packed in, packed out)
// ---------------------------------------------------------------------------
__global__ __launch_bounds__(256)
void fw_kernel(const u32* __restrict__ FR, const u32* __restrict__ FN,
               const float* __restrict__ attn2, u32* __restrict__ FW)
{
  const int b = blockIdx.z, c = blockIdx.y;
  const float a0 = attn2[b * 512 + c];
  const float a1 = attn2[b * 512 + 256 + c];
  const long base4 = ((long)b * 256 + c) * 1024;
  const int i = blockIdx.x * 256 + threadIdx.x;
  const uint4 r = ((const uint4*)FR)[base4 + i];
  const uint4 n = ((const uint4*)FN)[base4 + i];
  uint4 o;
  o.x = packf(a0 * unpackf(r.x) + a1 * unpackf(n.x));
  o.y = packf(a0 * unpackf(r.y) + a1 * unpackf(n.y));
  o.z = packf(a0 * unpackf(r.z) + a1 * unpackf(n.z));
  o.w = packf(a0 * unpackf(r.w) + a1 * unpackf(n.w));
  ((uint4*)FW)[base4 + i] = o;
}

// ---------------------------------------------------------------------------
// Depthwise 3x3, SAME padding; packed in/out; optional index-reversed copy.
// THREE jobs in ONE launch (blockIdx.y dispatch).
// ---------------------------------------------------------------------------
struct DwJob { const u32* in; const float* w; const float* bias; u32* out; u32* out_rev; };

__global__ __launch_bounds__(256)
void dw_kernel(DwJob j0, DwJob j1, DwJob j2)
{
  __shared__ float img[66][66];
  const int yy = blockIdx.y;
  const DwJob j = (yy == 0) ? j0 : ((yy == 1) ? j1 : j2);
  const int bc = blockIdx.x, tid = threadIdx.x;
  const int c = bc & 255;
  for (int v = tid; v < 66 * 66; v += 256) ((float*)img)[v] = 0.f;
  __syncthreads();
  const uint4* in4 = (const uint4*)(j.in + (long)bc * HW);
  for (int v = tid; v < 1024; v += 256) {
    const uint4 x = in4[v];
    const int r = v >> 4, c0 = ((v & 15) << 2) + 1;
    img[r + 1][c0 + 0] = unpackf(x.x);
    img[r + 1][c0 + 1] = unpackf(x.y);
    img[r + 1][c0 + 2] = unpackf(x.z);
    img[r + 1][c0 + 3] = unpackf(x.w);
  }
  float wr[9];
#pragma unroll
  for (int jj = 0; jj < 9; ++jj) wr[jj] = j.w[c * 9 + jj];
  const float bb = j.bias[c];
  __syncthreads();
  for (int p = tid; p < 4096; p += 256) {
    const int y = p >> 6, x = p & 63;
    float s = bb;
#pragma unroll
    for (int ky = 0; ky < 3; ++ky)
#pragma unroll
      for (int kx = 0; kx < 3; ++kx)
        s = fmaf(wr[ky * 3 + kx], img[y + ky][x + kx], s);
    const u32 u = packf(s);
    j.out[(long)bc * HW + p] = u;
    if (j.out_rev)
      j.out_rev[(long)bc * HW + (((64 - y) & 63) << 6) + ((64 - x) & 63)] = u;
  }
}

// ---------------------------------------------------------------------------
// S[b,c] = circconv2(Q[b,c], K[b,c]) via packed radix-4 FFTs.
// v5: TWO channels per block in TWO 32KB LDS buffers (ZA, ZB). Both forward
// FFTs run stage-interleaved between SHARED barriers; pair-owned pointwise
// writes the combined Hermitian spectrum C = P0 + i*P1 into ZA IN PLACE
// (zero cross-barrier register state); ONE inverse FFT yields S[2c] in Re,
// S[2c+1] in Im. 3 transforms per 2 channels. Stages 0+1 fused in registers;
// all twiddles in registers. LDS 64KB -> 2 blocks/CU.
// ---------------------------------------------------------------------------
#define SWA(r, c) (((r) << 6) | ((c) ^ (r)))
#define REV6(x)   ((((x) & 3) << 4) | ((x) & 12) | ((x) >> 4))

__device__ __forceinline__ float2 cmul(float2 a, float2 w) {
  return make_float2(a.x * w.x - a.y * w.y, a.x * w.y + a.y * w.x);
}
__device__ __forceinline__ float2 cmulc(float2 a, float2 w) {
  return make_float2(a.x * w.x + a.y * w.y, a.y * w.x - a.x * w.y);
}
// radix-4 DIT butterfly (inputs pre-twiddled), writes in-place p0..p3 order
__device__ __forceinline__ void r4fwd(float2& x0, float2& x1, float2& x2, float2& x3) {
  const float2 t0 = make_float2(x0.x + x2.x, x0.y + x2.y);
  const float2 t1 = make_float2(x0.x - x2.x, x0.y - x2.y);
  const float2 t2 = make_float2(x1.x + x3.x, x1.y + x3.y);
  const float2 t3 = make_float2(x1.x - x3.x, x1.y - x3.y);
  x0 = make_float2(t0.x + t2.x, t0.y + t2.y);
  x2 = make_float2(t0.x - t2.x, t0.y - t2.y);
  x1 = make_float2(t1.x + t3.y, t1.y - t3.x);
  x3 = make_float2(t1.x - t3.y, t1.y + t3.x);
}
// radix-4 inverse butterfly (outputs to be conj-twiddled by caller)
__device__ __forceinline__ void r4inv(float2& x0, float2& x1, float2& x2, float2& x3) {
  const float2 t0 = make_float2(x0.x + x2.x, x0.y + x2.y);
  const float2 t1 = make_float2(x0.x - x2.x, x0.y - x2.y);
  const float2 t2 = make_float2(x1.x + x3.x, x1.y + x3.y);
  const float2 t3 = make_float2(x1.x - x3.x, x1.y - x3.y);
  x0 = make_float2(t0.x + t2.x, t0.y + t2.y);
  x2 = make_float2(t0.x - t2.x, t0.y - t2.y);
  x1 = make_float2(t1.x - t3.y, t1.y + t3.x);
  x3 = make_float2(t1.x + t3.y, t1.y - t3.x);
}

// fused stages 0 (h=1) + 1 (h=4): 16-pt block [16kb,16kb+15], no barrier
__device__ __forceinline__ void fused01_fwd(float2* __restrict__ Z,
                                            const float2 (&wA)[3][3],
                                            int lane, int kb, int pass)
{
  float2 x[16];
#pragma unroll
  for (int m = 0; m < 16; ++m) {
    const int p = 16 * kb + m;
    x[m] = Z[pass ? SWA(p, lane) : SWA(lane, p)];
  }
#pragma unroll
  for (int c = 0; c < 4; ++c)
    r4fwd(x[4*c], x[4*c+1], x[4*c+2], x[4*c+3]);
#pragma unroll
  for (int j = 0; j < 4; ++j) {
    if (j) {
      x[j+4]  = cmul(x[j+4],  wA[j-1][0]);
      x[j+8]  = cmul(x[j+8],  wA[j-1][1]);
      x[j+12] = cmul(x[j+12], wA[j-1][2]);
    }
    r4fwd(x[j], x[j+4], x[j+8], x[j+12]);
  }
#pragma unroll
  for (int m = 0; m < 16; ++m) {
    const int p = 16 * kb + m;
    Z[pass ? SWA(p, lane) : SWA(lane, p)] = x[m];
  }
}

// stage 2 (h=16), no barrier
__device__ __forceinline__ void stage2_fwd(float2* __restrict__ Z,
                                           const float2 (&wB)[4][3],
                                           int lane, int kb, int pass)
{
#pragma unroll
  for (int q = 0; q < 4; ++q) {
    const int k = kb + 4 * q;
    const int a0 = pass ? SWA(k,      lane) : SWA(lane, k);
    const int a1 = pass ? SWA(k + 16, lane) : SWA(lane, k + 16);
    const int a2 = pass ? SWA(k + 32, lane) : SWA(lane, k + 32);
    const int a3 = pass ? SWA(k + 48, lane) : SWA(lane, k + 48);
    float2 x0 = Z[a0], x1 = Z[a1], x2 = Z[a2], x3 = Z[a3];
    x1 = cmul(x1, wB[q][0]);
    x2 = cmul(x2, wB[q][1]);
    x3 = cmul(x3, wB[q][2]);
    r4fwd(x0, x1, x2, x3);
    Z[a0] = x0; Z[a1] = x1; Z[a2] = x2; Z[a3] = x3;
  }
}

__device__ __forceinline__ void stage2_inv(float2* __restrict__ Z,
                                           const float2 (&wB)[4][3],
                                           int lane, int kb, int pass)
{
#pragma unroll
  for (int q = 0; q < 4; ++q) {
    const int k = kb + 4 * q;
    const int a0 = pass ? SWA(lane, k)      : SWA(k,      lane);
    const int a1 = pass ? SWA(lane, k + 16) : SWA(k + 16, lane);
    const int a2 = pass ? SWA(lane, k + 32) : SWA(k + 32, lane);
    const int a3 = pass ? SWA(lane, k + 48) : SWA(k + 48, lane);
    float2 x0 = Z[a0], x1 = Z[a1], x2 = Z[a2], x3 = Z[a3];
    r4inv(x0, x1, x2, x3);
    x1 = cmulc(x1, wB[q][0]);
    x2 = cmulc(x2, wB[q][1]);
    x3 = cmulc(x3, wB[q][2]);
    Z[a0] = x0; Z[a1] = x1; Z[a2] = x2; Z[a3] = x3;
  }
}

__device__ __forceinline__ void fused01_inv(float2* __restrict__ Z,
                                            const float2 (&wA)[3][3],
                                            int lane, int kb, int pass)
{
  float2 x[16];
#pragma unroll
  for (int m = 0; m < 16; ++m) {
    const int p = 16 * kb + m;
    x[m] = Z[pass ? SWA(lane, p) : SWA(p, lane)];
  }
#pragma unroll
  for (int j = 0; j < 4; ++j) {
    r4inv(x[j], x[j+4], x[j+8], x[j+12]);
    if (j) {
      x[j+4]  = cmulc(x[j+4],  wA[j-1][0]);
      x[j+8]  = cmulc(x[j+8],  wA[j-1][1]);
      x[j+12] = cmulc(x[j+12], wA[j-1][2]);
    }
  }
#pragma unroll
  for (int c = 0; c < 4; ++c)
    r4inv(x[4*c], x[4*c+1], x[4*c+2], x[4*c+3]);
#pragma unroll
  for (int m = 0; m < 16; ++m) {
    const int p = 16 * kb + m;
    Z[pass ? SWA(lane, p) : SWA(p, lane)] = x[m];
  }
}

// load Q + iK (bit-reversed rows, digit-reversed col groups, SWA swizzle)
__device__ __forceinline__ void sconv_load(float2* __restrict__ Z,
                                           const u32* __restrict__ Qg,
                                           const u32* __restrict__ Kg,
                                           long base, int tid)
{
  const uint4* Q4 = (const uint4*)(Qg + base);
  const uint4* K4 = (const uint4*)(Kg + base);
#pragma unroll
  for (int i = 0; i < 4; ++i) {
    const int v = tid + 256 * i;
    const uint4 q = Q4[v], k = K4[v];
    const int r = v >> 4, w = v & 15;
    const int R  = REV6(r);
    const int cb = ((w & 3) << 2) | (w >> 2);
    Z[SWA(R, cb)]      = make_float2(unpackf(q.x), unpackf(k.x));
    Z[SWA(R, cb + 16)] = make_float2(unpackf(q.y), unpackf(k.y));
    Z[SWA(R, cb + 32)] = make_float2(unpackf(q.z), unpackf(k.z));
    Z[SWA(R, cb + 48)] = make_float2(unpackf(q.w), unpackf(k.w));
  }
}

__global__ __launch_bounds__(256, 2)
void sconv_kernel(const u32* __restrict__ Qg, const u32* __restrict__ Kg,
                  u32* __restrict__ Sg)
{
  __shared__ float2 ZA[4096];    // channel 2c   (32 KB)
  __shared__ float2 ZB[4096];    // channel 2c+1 (32 KB)
  const int tid  = threadIdx.x;
  const int lane = tid & 63;
  const int kb   = tid >> 6;
  const long base = (long)blockIdx.x * 8192;   // two channels per block

  // register twiddles. wA: compile-time (twt[t] = e^{-2pi i t/64}):
  // {t=4,8,12},{8,16,24},{12,24,36}
  const float2 wA[3][3] = {
    { make_float2( 0.92387953251f, -0.38268343236f),
      make_float2( 0.70710678119f, -0.70710678119f),
      make_float2( 0.38268343236f, -0.92387953251f) },
    { make_float2( 0.70710678119f, -0.70710678119f),
      make_float2( 0.f,            -1.f),
      make_float2(-0.70710678119f, -0.70710678119f) },
    { make_float2( 0.38268343236f, -0.92387953251f),
      make_float2(-0.70710678119f, -0.70710678119f),
      make_float2(-0.92387953251f,  0.38268343236f) } };
  float2 wB[4][3];
#pragma unroll
  for (int q = 0; q < 4; ++q) {
    const float k = (float)(kb + 4 * q);   // k <= 15; 3k <= 45 < 64, no mod
    float sn, cs;
    __sincosf(-2.f * (float)M_PI * (1.f / 64.f) * k,        &sn, &cs); wB[q][0] = make_float2(cs, sn);
    __sincosf(-2.f * (float)M_PI * (1.f / 64.f) * (2.f*k),  &sn, &cs); wB[q][1] = make_float2(cs, sn);
    __sincosf(-2.f * (float)M_PI * (1.f / 64.f) * (3.f*k),  &sn, &cs); wB[q][2] = make_float2(cs, sn);
  }

  sconv_load(ZA, Qg, Kg, base, tid);
  sconv_load(ZB, Qg, Kg, base + 4096, tid);
  __syncthreads();

  // two forward FFTs, stage-interleaved between shared barriers
  for (int pass = 0; pass < 2; ++pass) {
    fused01_fwd(ZA, wA, lane, kb, pass);
    fused01_fwd(ZB, wA, lane, kb, pass);
    __syncthreads();
    stage2_fwd(ZA, wB, lane, kb, pass);
    stage2_fwd(ZB, wB, lane, kb, pass);
    __syncthreads();
  }

  // pair-owned pointwise, combined Hermitian pack:  C = P0 + i*P1 -> ZA
#pragma unroll
  for (int i = 0; i < 9; ++i) {
    const int n = tid + 256 * i;
    if (n < 2112) {                       // rows 0..32
      const int u = n >> 6, vv = n & 63;
      if (!((u == 0 || u == 32) && vv > 32)) {
        const int u2 = (64 - u) & 63, v2 = (64 - vv) & 63;
        const int az = SWA(u, vv), am = SWA(u2, v2);
        const float2 z0 = ZA[az], m0 = ZA[am];
        const float2 z1 = ZB[az], m1 = ZB[am];
        const float dre0 = 0.25f * (z0.x*z0.x - z0.y*z0.y - m0.x*m0.x + m0.y*m0.y);
        const float dim0 = 0.5f  * (z0.x*z0.y + m0.x*m0.y);
        const float dre1 = 0.25f * (z1.x*z1.x - z1.y*z1.y - m1.x*m1.x + m1.y*m1.y);
        const float dim1 = 0.5f  * (z1.x*z1.y + m1.x*m1.y);
        ZA[az] = make_float2(dim0 + dre1, dim1 - dre0);
        ZA[am] = make_float2(dim0 - dre1, dim1 + dre0);
      }
    }
  }
  __syncthreads();

  // one inverse FFT on the combined spectrum
  for (int pass = 0; pass < 2; ++pass) {
    stage2_inv(ZA, wB, lane, kb, pass);
    __syncthreads();
    fused01_inv(ZA, wA, lane, kb, pass);
    __syncthreads();
  }

  // store: Re -> S[2c], Im -> S[2c+1]
  uint4* Sa = (uint4*)(Sg + base);
  uint4* Sb = (uint4*)(Sg + base + 4096);
#pragma unroll
  for (int i = 0; i < 4; ++i) {
    const int v = tid + 256 * i;
    const int y = v >> 4, w = v & 15;
    const int Rr = REV6(y);
    const int cb = ((w & 3) << 2) | (w >> 2);
    const float2 e0 = ZA[SWA(Rr, cb)];
    const float2 e1 = ZA[SWA(Rr, cb + 16)];
    const float2 e2 = ZA[SWA(Rr, cb + 32)];
    const float2 e3 = ZA[SWA(Rr, cb + 48)];
    uint4 o;
    o.x = packf(e0.x * (1.f / 4096.f));
    o.y = packf(e1.x * (1.f / 4096.f));
    o.z = packf(e2.x * (1.f / 4096.f));
    o.w = packf(e3.x * (1.f / 4096.f));
    Sa[v] = o;
    o.x = packf(e0.y * (1.f / 4096.f));
    o.y = packf(e1.y * (1.f / 4096.f));
    o.z = packf(e2.y * (1.f / 4096.f));
    o.w = packf(e3.y * (1.f / 4096.f));
    Sb[v] = o;
  }
}

// ---------------------------------------------------------------------------
// Fused split-K reduce + row softmax; writes PACKED attn weights.
// ---------------------------------------------------------------------------
__global__ __launch_bounds__(256)
void softmax_kernel(const float* __restrict__ Lp, u32* __restrict__ L,
                    const float* __restrict__ alpha)
{
  __shared__ float red[256];
  const int row = blockIdx.x, tid = threadIdx.x;
  const int b = row >> 8, c = row & 255;
  const float sc = 4096.f / alpha[0];
  float acc = 0.f;
#pragma unroll
  for (int s = 0; s < SPLITK; ++s)
    acc += Lp[((long)(b * SPLITK + s) * 65536) + (long)c * 256 + tid];
  const float v = fabsf(acc) * sc;
  red[tid] = v; __syncthreads();
  for (int o = 128; o > 0; o >>= 1) {
    if (tid < o) red[tid] = fmaxf(red[tid], red[tid + o]);
    __syncthreads();
  }
  const float mx = red[0];
  __syncthreads();
  const float e = expf(v - mx);
  red[tid] = e; __syncthreads();
  for (int o = 128; o > 0; o >>= 1) {
    if (tid < o) red[tid] += red[tid + o];
    __syncthreads();
  }
  L[(long)row * 256 + tid] = packf(e / red[0]);
}

// ---------------------------------------------------------------------------
extern "C" void kernel_launch(void* const* d_in, const int* in_sizes, int n_in,
                              void* d_out, int out_size, void* d_ws, size_t ws_size,
                              hipStream_t stream)
{
  const float* x1       = (const float*)d_in[0];
  const float* x2       = (const float*)d_in[1];
  const float* conv_r_w = (const float*)d_in[2];
  const float* conv_r_b = (const float*)d_in[3];
  const float* conv_n_w = (const float*)d_in[4];
  const float* conv_n_b = (const float*)d_in[5];
  const float* mlp_w1   = (const float*)d_in[6];
  const float* mlp_w2   = (const float*)d_in[7];
  const float* pq_w     = (const float*)d_in[8];
  const float* pq_b     = (const float*)d_in[9];
  const float* dq_w     = (const float*)d_in[10];
  const float* dq_b     = (const float*)d_in[11];
  const float* pk_w     = (const float*)d_in[12];
  const float* pk_b     = (const float*)d_in[13];
  const float* dk_w     = (const float*)d_in[14];
  const float* dk_b     = (const float*)d_in[15];
  const float* pv_w     = (const float*)d_in[16];
  const float* pv_b     = (const float*)d_in[17];
  const float* dv_w     = (const float*)d_in[18];
  const float* dv_b     = (const float*)d_in[19];
  const float* out_w    = (const float*)d_in[20];
  const float* out_b    = (const float*)d_in[21];
  const float* alpha    = (const float*)d_in[22];
  const float* lambd    = (const float*)d_in[23];
  const float* beta     = (const float*)d_in[24];

  u32* s = (u32*)d_ws;
  u32* S0 = s;             // FR  -> Q        (packed)
  u32* S1 = s + SLOT;      // FN  -> K        (packed)
  u32* S2 = s + 2 * SLOT;  // Fw  -> mix      (packed, in-place)
  u32* S3 = s + 3 * SLOT;  // Pq  -> Krev     (packed)
  u32* S4 = s + 4 * SLOT;  // Pk  -> V        (packed)
  u32* S5 = s + 5 * SLOT;  // Pv  -> S        (packed)
  float* Lp     = (float*)(s + 6 * SLOT);             // [8][SPLITK][256][256] fp32
  u32*   Lb     = (u32*)(Lp + (long)8 * SPLITK * 65536);  // packed attn weights
  float* pooled = (float*)(Lb + (long)8 * 65536);
  float* attn2  = pooled + 2048;
  u32*   wR     = (u32*)(attn2 + 4096);               // packed weights
  u32*   wN     = wR + 65536;
  u32*   wQ     = wN + 32768;
  u32*   wK     = wQ + 65536;
  u32*   wV     = wK + 65536;
  u32*   wO     = wV + 65536;

  const size_t needed =
      (size_t)(6 * SLOT + (long)8 * SPLITK * 65536 + 8L * 65536 + 2048 + 4096
               + 65536 * 5 + 32768) * 4;
  if (ws_size < needed) return;

  const long ST2 = (long)128 * HW;
  const long STL = (long)256 * 256;

  // pre-split all six weight tensors to packed format in ONE launch
  {
    CvtJob jR{conv_r_w, wR, 16384};
    CvtJob jQ{pq_w,     wQ, 16384};
    CvtJob jK{pk_w,     wK, 16384};
    CvtJob jV{pv_w,     wV, 16384};
    CvtJob jO{out_w,    wO, 16384};
    CvtJob jN{conv_n_w, wN, 8192};
    cvt_kernel<<<dim3(64, 6), 256, 0, stream>>>(jR, jQ, jK, jV, jO, jN);
  }

  // FR = conv_r(x1) + FN = conv_n(x2) fused into ONE launch (co-residency)
  {
    GemmSet gR{wR, (const void*)x1, (void*)S0, conv_r_b, 256, ST};
    GemmSet gN{wN, (const void*)x2, (void*)S1, conv_n_b, 128, ST2};
    gemm_mfma<false, 1><<<dim3(32, 2, 8), 512, 0, stream>>>(gR, gN, gN,
        0L, ST, nullptr, nullptr, nullptr, nullptr, nullptr);
  }

  pool_kernel<<<2048, 256, 0, stream>>>(S0, S1, pooled);
  attn2_kernel<<<8, 256, 0, stream>>>(pooled, mlp_w1, mlp_w2, attn2);
  fw_kernel<<<dim3(4, 256, 8), 256, 0, stream>>>(S0, S1, attn2, S2);

  // Pq/Pk/Pv fused into ONE launch: same B (S2) -> same-XCD L2 sharing
  {
    GemmSet gQ{wQ, (const void*)S2, (void*)S3, pq_b, 256, ST};
    GemmSet gK{wK, (const void*)S2, (void*)S4, pk_b, 256, ST};
    GemmSet gV{wV, (const void*)S2, (void*)S5, pv_b, 256, ST};
    gemm_mfma<true, 1><<<dim3(32, 3, 8), 512, 0, stream>>>(gQ, gK, gV,
        0L, ST, nullptr, nullptr, nullptr, nullptr, nullptr);
  }

  // depthwise 3x3 (packed in/out), THREE jobs in ONE launch
  {
    DwJob jQ{S3, dq_w, dq_b, S0, nullptr};   // Q  -> S0
    DwJob jK{S4, dk_w, dk_b, S1, S3};        // K  -> S1, Krev -> S3
    DwJob jV{S5, dv_w, dv_b, S4, nullptr};   // V  -> S4
    dw_kernel<<<dim3(2048, 3), 256, 0, stream>>>(jQ, jK, jV);
  }

  // S = circconv2(Q, K)  — 2 channels/block, dual-LDS paired Hermitian inverse
  sconv_kernel<<<1024, 256, 0, stream>>>(S0, S1, S5);                // S -> S5

  // attn logits via MFMA split-K, then fused reduce+softmax (packed Lb)
  gemm_logits<<<dim3(2, 2, 64), 256, 0, stream>>>(S0, S3, Lp);
  softmax_kernel<<<2048, 256, 0, stream>>>(Lp, Lb, alpha);

  // cfr = attn_w @ S, fused mix epilogue (packed, in-place into S2)
  {
    GemmSet gM{Lb, (const void*)S5, (void*)S2, nullptr, 256, ST};
    gemm_mfma<true, 2><<<dim3(32, 1, 8), 512, 0, stream>>>(gM, gM, gM,
        STL, ST, S0, S4, S2, lambd, beta);
  }

  // final 1x1 conv -> d_out (fp32 + bias)
  {
    GemmSet gO{wO, (const void*)S2, d_out, out_b, 256, ST};
    gemm_mfma<true, 0><<<dim3(32, 1, 8), 512, 0, stream>>>(gO, gO, gO,
        0L, ST, nullptr, nullptr, nullptr, nullptr, nullptr);
  }
}

// Round 9
// 432.758 us; speedup vs baseline: 1.0185x; 1.0185x over previous
//
#include <hip/hip_runtime.h>
#include <math.h>

#ifndef M_PI
#define M_PI 3.14159265358979323846
#endif

typedef unsigned int u32;

// Problem constants
constexpr int  NB   = 8;
constexpr int  CH   = 256;
constexpr long HW   = 4096;                 // 64*64
constexpr long SLOT = (long)NB * CH * HW;   // elems per [8,256,64,64] tensor
constexpr int  SPLITK = 8;                  // logits GEMM split factor
constexpr long ST   = (long)CH * HW;        // 1048576

// ===========================================================================
// Packed split-bf16 format: u32 = bits(bf16_rne_hi(x)) | bits(bf16_trunc(lo))>>16
//   hi in top 16 bits, lo in low 16 bits; reconstruction error ~2^-17 relative.
// ===========================================================================
__device__ __forceinline__ float rne_hi(float x) {
  unsigned u = __float_as_uint(x);
  unsigned r = (u + 0x7FFFu + ((u >> 16) & 1u)) & 0xFFFF0000u;
  return __uint_as_float(r);
}
__device__ __forceinline__ u32 packf(float x) {
  const float h = rne_hi(x);
  const float l = x - h;
  return (__float_as_uint(h) & 0xFFFF0000u) | (__float_as_uint(l) >> 16);
}
__device__ __forceinline__ float unpackf(u32 u) {
  return __uint_as_float(u & 0xFFFF0000u) + __uint_as_float(u << 16);
}
__device__ __forceinline__ unsigned bfpair(float x, float y) {
  return (__float_as_uint(x) >> 16) | (__float_as_uint(y) & 0xFFFF0000u);
}

typedef short bf16x8 __attribute__((ext_vector_type(8)));
typedef float f32x4  __attribute__((ext_vector_type(4)));

// ===========================================================================
// cvt: fp32 -> packed u32; SIX tensors in ONE launch (blockIdx.y dispatch)
// ===========================================================================
struct CvtJob { const float* src; u32* dst; int n4; };

__global__ __launch_bounds__(256)
void cvt_kernel(CvtJob j0, CvtJob j1, CvtJob j2, CvtJob j3, CvtJob j4, CvtJob j5)
{
  const int yy = blockIdx.y;
  CvtJob j;
  switch (yy) {
    case 0: j = j0; break;
    case 1: j = j1; break;
    case 2: j = j2; break;
    case 3: j = j3; break;
    case 4: j = j4; break;
    default: j = j5; break;
  }
  const int i = blockIdx.x * 256 + threadIdx.x;
  if (i < j.n4) {
    const float4 v = ((const float4*)j.src)[i];
    uint4 o;
    o.x = packf(v.x); o.y = packf(v.y); o.z = packf(v.z); o.w = packf(v.w);
    ((uint4*)j.dst)[i] = o;
  }
}

// ===========================================================================
// MFMA split-bf16 GEMM: C[b](256 x 4096) = A[b](256 x K) * B[b](K x 4096)
// A always packed-u32 [M][K]. B: BPACKED ? packed-u32 [K][N] : fp32 [K][N].
// 3-product emulation: C ~= Ah*Bh + Ah*Bl + Al*Bh.
// v9: DOUBLE-BUFFERED single-barrier pipeline (catalog minimum-2-phase).
// r8 post-mortem: 2 barriers/k-tile with full vmcnt drain was the stall
// (co-residency levers were null: LDS 72->48KB gave 0%, occupancy pinned).
// Per k-tile: issue global loads(t+1) EARLY -> ds_read+MFMA on LDS[cur]
// (hides ~500cy HBM latency under ~1000cy compute) -> commit regs->LDS[cur^1]
// (vmcnt waited here, after compute) -> ONE barrier -> swap. WAR-safe: buf X
// recommitted only after the barrier ending the iteration that read it.
// Padded stride-48 LDS restored (r8 chunk-swizzle DOUBLED bank conflicts).
// LDS 2x72KB = 144KB -> 1 block/CU (extra blocks proven worthless r7/r8).
// Block tile 256x128 (full M), 512 threads = 8 waves (4m x 2n).
// Multi-problem blockIdx.y dispatch kept (QKV same-B L2 share: FETCH 221->30MB).
// EPI 0: fp32 +bias. EPI 1: packed +bias. EPI 2: fused mix -> packed.
// ===========================================================================
struct GemmSet {
  const u32*   A;        // packed weights / logits
  const void*  B;        // activation
  void*        C;        // output
  const float* bias;     // nullable
  int          K;
  long         bStride;  // B batch stride (elements)
};

__device__ __forceinline__ void commitA48(unsigned short* __restrict__ dh,
                                          unsigned short* __restrict__ dl,
                                          const u32* ra, int aBase)
{
  u32 hi[8], lo[8];
#pragma unroll
  for (int e = 0; e < 8; ++e) {
    const u32 u0 = ra[2*e], u1 = ra[2*e+1];
    hi[e] = (u0 >> 16) | (u1 & 0xFFFF0000u);
    lo[e] = (u0 & 0xFFFFu) | (u1 << 16);
  }
  *(uint4*)&dh[aBase]     = make_uint4(hi[0], hi[1], hi[2], hi[3]);
  *(uint4*)&dh[aBase + 8] = make_uint4(hi[4], hi[5], hi[6], hi[7]);
  *(uint4*)&dl[aBase]     = make_uint4(lo[0], lo[1], lo[2], lo[3]);
  *(uint4*)&dl[aBase + 8] = make_uint4(lo[4], lo[5], lo[6], lo[7]);
}

__device__ __forceinline__ void commitBu48(unsigned short* __restrict__ dh,
                                           unsigned short* __restrict__ dl,
                                           const u32* rbu, int bBase)
{
  u32 hi[4], lo[4];
#pragma unroll
  for (int e = 0; e < 4; ++e) {
    const u32 u0 = rbu[2*e], u1 = rbu[2*e+1];
    hi[e] = (u0 >> 16) | (u1 & 0xFFFF0000u);
    lo[e] = (u0 & 0xFFFFu) | (u1 << 16);
  }
  *(uint4*)&dh[bBase] = make_uint4(hi[0], hi[1], hi[2], hi[3]);
  *(uint4*)&dl[bBase] = make_uint4(lo[0], lo[1], lo[2], lo[3]);
}

__device__ __forceinline__ void commitBf48(unsigned short* __restrict__ dh,
                                           unsigned short* __restrict__ dl,
                                           const float* rbf, int bBase)
{
  float h[8], l[8];
#pragma unroll
  for (int e = 0; e < 8; ++e) { h[e] = rne_hi(rbf[e]); l[e] = rbf[e] - h[e]; }
  *(uint4*)&dh[bBase] = make_uint4(bfpair(h[0],h[1]), bfpair(h[2],h[3]),
                                   bfpair(h[4],h[5]), bfpair(h[6],h[7]));
  *(uint4*)&dl[bBase] = make_uint4(bfpair(l[0],l[1]), bfpair(l[2],l[3]),
                                   bfpair(l[4],l[5]), bfpair(l[6],l[7]));
}

template<bool BPACKED, int EPI>
__global__ __launch_bounds__(512, 2)
void gemm_mfma(GemmSet g0, GemmSet g1, GemmSet g2,
               long aStride, long cStride,
               const u32* __restrict__ qb, const u32* __restrict__ vb,
               const u32* __restrict__ fwb,
               const float* __restrict__ lambd, const float* __restrict__ beta)
{
  constexpr int N = 4096;
  __shared__ __align__(16) unsigned short sAh[2][256 * 48];
  __shared__ __align__(16) unsigned short sAl[2][256 * 48];
  __shared__ __align__(16) unsigned short sBh[2][128 * 48];
  __shared__ __align__(16) unsigned short sBl[2][128 * 48];

  const int tid = threadIdx.x;
  const int b   = blockIdx.z;
  const int yy  = blockIdx.y;
  const int n0  = blockIdx.x * 128;

  const GemmSet g = (yy == 0) ? g0 : ((yy == 1) ? g1 : g2);
  const u32*   A       = g.A;
  const void*  Bv      = g.B;
  void*        Cv      = g.C;
  const float* bias    = g.bias;
  const int    K       = g.K;
  const long   bStride = g.bStride;

  const u32* Ab = A + (long)b * aStride;

  const int ar = tid >> 1;            // 0..255 (full M rows)
  const int ak = (tid & 1) * 16;      // k-offset (shorts) for global load
  const int aBase = ar * 48 + ak;
  const int bn = tid & 127;           // 0..127 (n within tile)
  const int bk = (tid >> 7) * 8;      // {0,8,16,24}
  const int bBase = bn * 48 + bk;

  const int wv = tid >> 6, lane = tid & 63;
  const int wy = wv >> 1, wx = wv & 1;   // wy 0..3 (m), wx 0..1 (n)
  const int quad = lane >> 4, l15 = lane & 15;

  f32x4 acc[4][4];
#pragma unroll
  for (int i = 0; i < 4; ++i)
#pragma unroll
    for (int j = 0; j < 4; ++j) acc[i][j] = (f32x4){0.f, 0.f, 0.f, 0.f};

  u32   ra[16];
  u32   rbu[8];
  float rbf[8];

  // prologue: load tile 0 -> regs, commit -> buffer 0
  {
    const u32* ap = Ab + (long)ar * K + ak;
#pragma unroll
    for (int i = 0; i < 4; ++i) {
      const uint4 t = *(const uint4*)(ap + i * 4);
      ra[4*i] = t.x; ra[4*i+1] = t.y; ra[4*i+2] = t.z; ra[4*i+3] = t.w;
    }
    if (BPACKED) {
      const u32* bp = (const u32*)Bv + (long)b * bStride + (long)bk * N + n0 + bn;
#pragma unroll
      for (int i = 0; i < 8; ++i) rbu[i] = bp[(long)i * N];
    } else {
      const float* bp = (const float*)Bv + (long)b * bStride + (long)bk * N + n0 + bn;
#pragma unroll
      for (int i = 0; i < 8; ++i) rbf[i] = bp[(long)i * N];
    }
  }
  commitA48(sAh[0], sAl[0], ra, aBase);
  if (BPACKED) commitBu48(sBh[0], sBl[0], rbu, bBase);
  else         commitBf48(sBh[0], sBl[0], rbf, bBase);
  __syncthreads();

  int cur = 0;
  for (int kt = 0; kt < K; kt += 32) {
    const bool more = (kt + 32 < K);

    // issue next-tile global loads EARLY (latency hides under compute below)
    if (more) {
      const u32* ap = Ab + (long)ar * K + kt + 32 + ak;
#pragma unroll
      for (int i = 0; i < 4; ++i) {
        const uint4 t = *(const uint4*)(ap + i * 4);
        ra[4*i] = t.x; ra[4*i+1] = t.y; ra[4*i+2] = t.z; ra[4*i+3] = t.w;
      }
      if (BPACKED) {
        const u32* bp = (const u32*)Bv + (long)b * bStride + (long)(kt + 32 + bk) * N + n0 + bn;
#pragma unroll
        for (int i = 0; i < 8; ++i) rbu[i] = bp[(long)i * N];
      } else {
        const float* bp = (const float*)Bv + (long)b * bStride + (long)(kt + 32 + bk) * N + n0 + bn;
#pragma unroll
        for (int i = 0; i < 8; ++i) rbf[i] = bp[(long)i * N];
      }
    }

    // compute on buffer cur: fragments + 48 MFMA
    {
      const unsigned short* cAh = sAh[cur];
      const unsigned short* cAl = sAl[cur];
      const unsigned short* cBh = sBh[cur];
      const unsigned short* cBl = sBl[cur];
      bf16x8 ah[4], al[4];
#pragma unroll
      for (int i = 0; i < 4; ++i) {
        const int idx = (wy * 64 + i * 16 + l15) * 48 + quad * 8;
        ah[i] = *(const bf16x8*)&cAh[idx];
        al[i] = *(const bf16x8*)&cAl[idx];
      }
#pragma unroll
      for (int j = 0; j < 4; ++j) {
        const int idx = (wx * 64 + j * 16 + l15) * 48 + quad * 8;
        const bf16x8 bh = *(const bf16x8*)&cBh[idx];
        const bf16x8 bl = *(const bf16x8*)&cBl[idx];
#pragma unroll
        for (int i = 0; i < 4; ++i) {
          acc[i][j] = __builtin_amdgcn_mfma_f32_16x16x32_bf16(ah[i], bh, acc[i][j], 0, 0, 0);
          acc[i][j] = __builtin_amdgcn_mfma_f32_16x16x32_bf16(ah[i], bl, acc[i][j], 0, 0, 0);
          acc[i][j] = __builtin_amdgcn_mfma_f32_16x16x32_bf16(al[i], bh, acc[i][j], 0, 0, 0);
        }
      }
    }

    // commit next tile into the other buffer (vmcnt waits land here)
    if (more) {
      const int nb = cur ^ 1;
      commitA48(sAh[nb], sAl[nb], ra, aBase);
      if (BPACKED) commitBu48(sBh[nb], sBl[nb], rbu, bBase);
      else         commitBf48(sBh[nb], sBl[nb], rbf, bBase);
    }
    __syncthreads();
    if (more) cur ^= 1;
  }

  // epilogue
  if (EPI == 0) {
    float* Cb = (float*)Cv + (long)b * cStride;
#pragma unroll
    for (int i = 0; i < 4; ++i)
#pragma unroll
      for (int r = 0; r < 4; ++r) {
        const int row = wy * 64 + i * 16 + quad * 4 + r;
        const float bb = bias ? bias[row] : 0.f;
#pragma unroll
        for (int j = 0; j < 4; ++j) {
          const int col = n0 + wx * 64 + j * 16 + l15;
          Cb[(long)row * N + col] = acc[i][j][r] + bb;
        }
      }
  } else if (EPI == 1) {
    u32* Cb = (u32*)Cv + (long)b * cStride;
#pragma unroll
    for (int i = 0; i < 4; ++i)
#pragma unroll
      for (int r = 0; r < 4; ++r) {
        const int row = wy * 64 + i * 16 + quad * 4 + r;
        const float bb = bias ? bias[row] : 0.f;
#pragma unroll
        for (int j = 0; j < 4; ++j) {
          const int col = n0 + wx * 64 + j * 16 + l15;
          Cb[(long)row * N + col] = packf(acc[i][j][r] + bb);
        }
      }
  } else {
    u32* Cb = (u32*)Cv + (long)b * cStride;
    const float lam = lambd[0], bet = beta[0];
#pragma unroll
    for (int i = 0; i < 4; ++i)
#pragma unroll
      for (int r = 0; r < 4; ++r) {
        const int row = wy * 64 + i * 16 + quad * 4 + r;
#pragma unroll
        for (int j = 0; j < 4; ++j) {
          const int col = n0 + wx * 64 + j * 16 + l15;
          const long off = (long)row * N + col;
          const long gi  = (long)b * cStride + off;
          const float q = unpackf(qb[gi]);
          const float v = unpackf(vb[gi]);
          const float f = unpackf(fwb[gi]);
          Cb[off] = packf(bet * (acc[i][j][r] * (q - lam * v) + v) + (1.f - bet) * f);
        }
      }
  }
}

// ===========================================================================
// MFMA logits GEMM: Lp[b,s](256x256) = Q[b](256x4096) . Krev[b]^T over k-span s
// Both operands packed-u32, K-contiguous. Tile 128x128, split-K=8, BK=32.
// ===========================================================================
__global__ __launch_bounds__(256)
void gemm_logits(const u32* __restrict__ Q, const u32* __restrict__ Kr,
                 float* __restrict__ Lp)
{
  __shared__ __align__(16) unsigned short sAh[128 * 48];
  __shared__ __align__(16) unsigned short sAl[128 * 48];
  __shared__ __align__(16) unsigned short sBh[128 * 48];
  __shared__ __align__(16) unsigned short sBl[128 * 48];

  const int tid = threadIdx.x;
  const int bz  = blockIdx.z;            // b*8 + s
  const int b   = bz >> 3, sp = bz & 7;
  const int m0  = blockIdx.y * 128;
  const int n0  = blockIdx.x * 128;
  const long k0b = (long)sp * 512;

  const int ar = tid >> 1;
  const int ak = (tid & 1) * 16;
  const int aBase = ar * 48 + ak;

  const int wv = tid >> 6, lane = tid & 63;
  const int wy = wv >> 1, wx = wv & 1;
  const int quad = lane >> 4, l15 = lane & 15;

  f32x4 acc[4][4];
#pragma unroll
  for (int i = 0; i < 4; ++i)
#pragma unroll
    for (int j = 0; j < 4; ++j) acc[i][j] = (f32x4){0.f, 0.f, 0.f, 0.f};

  const u32* Abase = Q  + (long)b * ST + (long)(m0 + ar) * 4096 + k0b + ak;
  const u32* Bbase = Kr + (long)b * ST + (long)(n0 + ar) * 4096 + k0b + ak;

  u32 ra[16], rb[16];
#pragma unroll
  for (int i = 0; i < 4; ++i) {
    uint4 t = *(const uint4*)(Abase + i * 4);
    ra[4*i] = t.x; ra[4*i+1] = t.y; ra[4*i+2] = t.z; ra[4*i+3] = t.w;
    t = *(const uint4*)(Bbase + i * 4);
    rb[4*i] = t.x; rb[4*i+1] = t.y; rb[4*i+2] = t.z; rb[4*i+3] = t.w;
  }

  for (int kt = 0; kt < 512; kt += 32) {
    {
      u32 hi[8], lo[8];
#pragma unroll
      for (int e = 0; e < 8; ++e) {
        const u32 u0 = ra[2*e], u1 = ra[2*e+1];
        hi[e] = (u0 >> 16) | (u1 & 0xFFFF0000u);
        lo[e] = (u0 & 0xFFFFu) | (u1 << 16);
      }
      *(uint4*)&sAh[aBase]     = make_uint4(hi[0], hi[1], hi[2], hi[3]);
      *(uint4*)&sAh[aBase + 8] = make_uint4(hi[4], hi[5], hi[6], hi[7]);
      *(uint4*)&sAl[aBase]     = make_uint4(lo[0], lo[1], lo[2], lo[3]);
      *(uint4*)&sAl[aBase + 8] = make_uint4(lo[4], lo[5], lo[6], lo[7]);
#pragma unroll
      for (int e = 0; e < 8; ++e) {
        const u32 u0 = rb[2*e], u1 = rb[2*e+1];
        hi[e] = (u0 >> 16) | (u1 & 0xFFFF0000u);
        lo[e] = (u0 & 0xFFFFu) | (u1 << 16);
      }
      *(uint4*)&sBh[aBase]     = make_uint4(hi[0], hi[1], hi[2], hi[3]);
      *(uint4*)&sBh[aBase + 8] = make_uint4(hi[4], hi[5], hi[6], hi[7]);
      *(uint4*)&sBl[aBase]     = make_uint4(lo[0], lo[1], lo[2], lo[3]);
      *(uint4*)&sBl[aBase + 8] = make_uint4(lo[4], lo[5], lo[6], lo[7]);
    }
    __syncthreads();

    if (kt + 32 < 512) {
#pragma unroll
      for (int i = 0; i < 4; ++i) {
        uint4 t = *(const uint4*)(Abase + kt + 32 + i * 4);
        ra[4*i] = t.x; ra[4*i+1] = t.y; ra[4*i+2] = t.z; ra[4*i+3] = t.w;
        t = *(const uint4*)(Bbase + kt + 32 + i * 4);
        rb[4*i] = t.x; rb[4*i+1] = t.y; rb[4*i+2] = t.z; rb[4*i+3] = t.w;
      }
    }

    bf16x8 ah[4], al[4];
#pragma unroll
    for (int i = 0; i < 4; ++i) {
      const int idx = (wy * 64 + i * 16 + l15) * 48 + quad * 8;
      ah[i] = *(const bf16x8*)&sAh[idx];
      al[i] = *(const bf16x8*)&sAl[idx];
    }
#pragma unroll
    for (int j = 0; j < 4; ++j) {
      const int idx = (wx * 64 + j * 16 + l15) * 48 + quad * 8;
      const bf16x8 bh = *(const bf16x8*)&sBh[idx];
      const bf16x8 bl = *(const bf16x8*)&sBl[idx];
#pragma unroll
      for (int i = 0; i < 4; ++i) {
        acc[i][j] = __builtin_amdgcn_mfma_f32_16x16x32_bf16(ah[i], bh, acc[i][j], 0, 0, 0);
        acc[i][j] = __builtin_amdgcn_mfma_f32_16x16x32_bf16(ah[i], bl, acc[i][j], 0, 0, 0);
        acc[i][j] = __builtin_amdgcn_mfma_f32_16x16x32_bf16(al[i], bh, acc[i][j], 0, 0, 0);
      }
    }
    __syncthreads();
  }

  float* Lb = Lp + (long)bz * 65536;
#pragma unroll
  for (int i = 0; i < 4; ++i)
#pragma unroll
    for (int r = 0; r < 4; ++r) {
      const int row = m0 + wy * 64 + i * 16 + quad * 4 + r;
#pragma unroll
      for (int j = 0; j < 4; ++j) {
        const int col = n0 + wx * 64 + j * 16 + l15;
        Lb[(long)row * 256 + col] = acc[i][j][r];
      }
    }
}

// ---------------------------------------------------------------------------
// pooled[b,c] = mean over HW of (FR + FN)   (packed inputs)
// ---------------------------------------------------------------------------
__global__ __launch_bounds__(256)
void pool_kernel(const u32* __restrict__ FR, const u32* __restrict__ FN,
                 float* __restrict__ pooled)
{
  __shared__ float red[256];
  const int bc = blockIdx.x, tid = threadIdx.x;
  const uint4* a = (const uint4*)(FR + (long)bc * HW);
  const uint4* b = (const uint4*)(FN + (long)bc * HW);
  float s = 0.f;
  for (int v = tid; v < 1024; v += 256) {
    const uint4 x = a[v];
    s += unpackf(x.x) + unpackf(x.y) + unpackf(x.z) + unpackf(x.w);
    const uint4 y = b[v];
    s += unpackf(y.x) + unpackf(y.y) + unpackf(y.z) + unpackf(y.w);
  }
  red[tid] = s; __syncthreads();
  for (int o = 128; o > 0; o >>= 1) {
    if (tid < o) red[tid] += red[tid + o];
    __syncthreads();
  }
  if (tid == 0) pooled[bc] = red[0] * (1.f / 4096.f);
}

// ---------------------------------------------------------------------------
// MLP (relu) + 2-way softmax -> attn2 [8,2,256]  (fp32 throughout)
// ---------------------------------------------------------------------------
__global__ __launch_bounds__(256)
void attn2_kernel(const float* __restrict__ pooled, const float* __restrict__ w1,
                  const float* __restrict__ w2, float* __restrict__ attn2)
{
  __shared__ float ps[256];
  __shared__ float hs[32];
  const int b = blockIdx.x, tid = threadIdx.x;
  ps[tid] = pooled[b * 256 + tid];
  __syncthreads();
  if (tid < 32) {
    float a = 0.f;
    for (int c = 0; c < 256; ++c) a += ps[c] * w1[tid * 256 + c];
    hs[tid] = fmaxf(a, 0.f);
  }
  __syncthreads();
  float a0 = 0.f, a1 = 0.f;
  for (int d = 0; d < 32; ++d) {
    const float h = hs[d];
    a0 += h * w2[tid * 32 + d];
    a1 += h * w2[(256 + tid) * 32 + d];
  }
  const float m  = fmaxf(a0, a1);
  const float e0 = expf(a0 - m), e1 = expf(a1 - m);
  const float inv = 1.f / (e0 + e1);
  attn2[b * 512 + tid]       = e0 * inv;
  attn2[b * 512 + 256 + tid] = e1 * inv;
}

// ---------------------------------------------------------------------------
// Fw = a0*FR + a1*FN   (packed in, packed out)
// ---------------------------------------------------------------------------
__global__ __launch_bounds__(256)
void fw_kernel(const u32* __restrict__ FR, const u32* __restrict__ FN,
               const float* __restrict__ attn2, u32* __restrict__ FW)
{
  const int b = blockIdx.z, c = blockIdx.y;
  const float a0 = attn2[b * 512 + c];
  const float a1 = attn2[b * 512 + 256 + c];
  const long base4 = ((long)b * 256 + c) * 1024;
  const int i = blockIdx.x * 256 + threadIdx.x;
  const uint4 r = ((const uint4*)FR)[base4 + i];
  const uint4 n = ((const uint4*)FN)[base4 + i];
  uint4 o;
  o.x = packf(a0 * unpackf(r.x) + a1 * unpackf(n.x));
  o.y = packf(a0 * unpackf(r.y) + a1 * unpackf(n.y));
  o.z = packf(a0 * unpackf(r.z) + a1 * unpackf(n.z));
  o.w = packf(a0 * unpackf(r.w) + a1 * unpackf(n.w));
  ((uint4*)FW)[base4 + i] = o;
}

// ---------------------------------------------------------------------------
// Depthwise 3x3, SAME padding; packed in/out; optional index-reversed copy.
// THREE jobs in ONE launch (blockIdx.y dispatch).
// ---------------------------------------------------------------------------
struct DwJob { const u32* in; const float* w; const float* bias; u32* out; u32* out_rev; };

__global__ __launch_bounds__(256)
void dw_kernel(DwJob j0, DwJob j1, DwJob j2)
{
  __shared__ float img[66][66];
  const int yy = blockIdx.y;
  const DwJob j = (yy == 0) ? j0 : ((yy == 1) ? j1 : j2);
  const int bc = blockIdx.x, tid = threadIdx.x;
  const int c = bc & 255;
  for (int v = tid; v < 66 * 66; v += 256) ((float*)img)[v] = 0.f;
  __syncthreads();
  const uint4* in4 = (const uint4*)(j.in + (long)bc * HW);
  for (int v = tid; v < 1024; v += 256) {
    const uint4 x = in4[v];
    const int r = v >> 4, c0 = ((v & 15) << 2) + 1;
    img[r + 1][c0 + 0] = unpackf(x.x);
    img[r + 1][c0 + 1] = unpackf(x.y);
    img[r + 1][c0 + 2] = unpackf(x.z);
    img[r + 1][c0 + 3] = unpackf(x.w);
  }
  float wr[9];
#pragma unroll
  for (int jj = 0; jj < 9; ++jj) wr[jj] = j.w[c * 9 + jj];
  const float bb = j.bias[c];
  __syncthreads();
  for (int p = tid; p < 4096; p += 256) {
    const int y = p >> 6, x = p & 63;
    float s = bb;
#pragma unroll
    for (int ky = 0; ky < 3; ++ky)
#pragma unroll
      for (int kx = 0; kx < 3; ++kx)
        s = fmaf(wr[ky * 3 + kx], img[y + ky][x + kx], s);
    const u32 u = packf(s);
    j.out[(long)bc * HW + p] = u;
    if (j.out_rev)
      j.out_rev[(long)bc * HW + (((64 - y) & 63) << 6) + ((64 - x) & 63)] = u;
  }
}

// ---------------------------------------------------------------------------
// S[b,c] = circconv2(Q[b,c], K[b,c]) via packed radix-4 FFTs.
// v5: TWO channels per block in TWO 32KB LDS buffers (ZA, ZB). Both forward
// FFTs run stage-interleaved between SHARED barriers; pair-owned pointwise
// writes the combined Hermitian spectrum C = P0 + i*P1 into ZA IN PLACE
// (zero cross-barrier register state); ONE inverse FFT yields S[2c] in Re,
// S[2c+1] in Im. 3 transforms per 2 channels. Stages 0+1 fused in registers;
// all twiddles in registers. LDS 64KB -> 2 blocks/CU.
// ---------------------------------------------------------------------------
#define SWA(r, c) (((r) << 6) | ((c) ^ (r)))
#define REV6(x)   ((((x) & 3) << 4) | ((x) & 12) | ((x) >> 4))

__device__ __forceinline__ float2 cmul(float2 a, float2 w) {
  return make_float2(a.x * w.x - a.y * w.y, a.x * w.y + a.y * w.x);
}
__device__ __forceinline__ float2 cmulc(float2 a, float2 w) {
  return make_float2(a.x * w.x + a.y * w.y, a.y * w.x - a.x * w.y);
}
// radix-4 DIT butterfly (inputs pre-twiddled), writes in-place p0..p3 order
__device__ __forceinline__ void r4fwd(float2& x0, float2& x1, float2& x2, float2& x3) {
  const float2 t0 = make_float2(x0.x + x2.x, x0.y + x2.y);
  const float2 t1 = make_float2(x0.x - x2.x, x0.y - x2.y);
  const float2 t2 = make_float2(x1.x + x3.x, x1.y + x3.y);
  const float2 t3 = make_float2(x1.x - x3.x, x1.y - x3.y);
  x0 = make_float2(t0.x + t2.x, t0.y + t2.y);
  x2 = make_float2(t0.x - t2.x, t0.y - t2.y);
  x1 = make_float2(t1.x + t3.y, t1.y - t3.x);
  x3 = make_float2(t1.x - t3.y, t1.y + t3.x);
}
// radix-4 inverse butterfly (outputs to be conj-twiddled by caller)
__device__ __forceinline__ void r4inv(float2& x0, float2& x1, float2& x2, float2& x3) {
  const float2 t0 = make_float2(x0.x + x2.x, x0.y + x2.y);
  const float2 t1 = make_float2(x0.x - x2.x, x0.y - x2.y);
  const float2 t2 = make_float2(x1.x + x3.x, x1.y + x3.y);
  const float2 t3 = make_float2(x1.x - x3.x, x1.y - x3.y);
  x0 = make_float2(t0.x + t2.x, t0.y + t2.y);
  x2 = make_float2(t0.x - t2.x, t0.y - t2.y);
  x1 = make_float2(t1.x - t3.y, t1.y + t3.x);
  x3 = make_float2(t1.x + t3.y, t1.y - t3.x);
}

// fused stages 0 (h=1) + 1 (h=4): 16-pt block [16kb,16kb+15], no barrier
__device__ __forceinline__ void fused01_fwd(float2* __restrict__ Z,
                                            const float2 (&wA)[3][3],
                                            int lane, int kb, int pass)
{
  float2 x[16];
#pragma unroll
  for (int m = 0; m < 16; ++m) {
    const int p = 16 * kb + m;
    x[m] = Z[pass ? SWA(p, lane) : SWA(lane, p)];
  }
#pragma unroll
  for (int c = 0; c < 4; ++c)
    r4fwd(x[4*c], x[4*c+1], x[4*c+2], x[4*c+3]);
#pragma unroll
  for (int j = 0; j < 4; ++j) {
    if (j) {
      x[j+4]  = cmul(x[j+4],  wA[j-1][0]);
      x[j+8]  = cmul(x[j+8],  wA[j-1][1]);
      x[j+12] = cmul(x[j+12], wA[j-1][2]);
    }
    r4fwd(x[j], x[j+4], x[j+8], x[j+12]);
  }
#pragma unroll
  for (int m = 0; m < 16; ++m) {
    const int p = 16 * kb + m;
    Z[pass ? SWA(p, lane) : SWA(lane, p)] = x[m];
  }
}

// stage 2 (h=16), no barrier
__device__ __forceinline__ void stage2_fwd(float2* __restrict__ Z,
                                           const float2 (&wB)[4][3],
                                           int lane, int kb, int pass)
{
#pragma unroll
  for (int q = 0; q < 4; ++q) {
    const int k = kb + 4 * q;
    const int a0 = pass ? SWA(k,      lane) : SWA(lane, k);
    const int a1 = pass ? SWA(k + 16, lane) : SWA(lane, k + 16);
    const int a2 = pass ? SWA(k + 32, lane) : SWA(lane, k + 32);
    const int a3 = pass ? SWA(k + 48, lane) : SWA(lane, k + 48);
    float2 x0 = Z[a0], x1 = Z[a1], x2 = Z[a2], x3 = Z[a3];
    x1 = cmul(x1, wB[q][0]);
    x2 = cmul(x2, wB[q][1]);
    x3 = cmul(x3, wB[q][2]);
    r4fwd(x0, x1, x2, x3);
    Z[a0] = x0; Z[a1] = x1; Z[a2] = x2; Z[a3] = x3;
  }
}

__device__ __forceinline__ void stage2_inv(float2* __restrict__ Z,
                                           const float2 (&wB)[4][3],
                                           int lane, int kb, int pass)
{
#pragma unroll
  for (int q = 0; q < 4; ++q) {
    const int k = kb + 4 * q;
    const int a0 = pass ? SWA(lane, k)      : SWA(k,      lane);
    const int a1 = pass ? SWA(lane, k + 16) : SWA(k + 16, lane);
    const int a2 = pass ? SWA(lane, k + 32) : SWA(k + 32, lane);
    const int a3 = pass ? SWA(lane, k + 48) : SWA(k + 48, lane);
    float2 x0 = Z[a0], x1 = Z[a1], x2 = Z[a2], x3 = Z[a3];
    r4inv(x0, x1, x2, x3);
    x1 = cmulc(x1, wB[q][0]);
    x2 = cmulc(x2, wB[q][1]);
    x3 = cmulc(x3, wB[q][2]);
    Z[a0] = x0; Z[a1] = x1; Z[a2] = x2; Z[a3] = x3;
  }
}

__device__ __forceinline__ void fused01_inv(float2* __restrict__ Z,
                                            const float2 (&wA)[3][3],
                                            int lane, int kb, int pass)
{
  float2 x[16];
#pragma unroll
  for (int m = 0; m < 16; ++m) {
    const int p = 16 * kb + m;
    x[m] = Z[pass ? SWA(lane, p) : SWA(p, lane)];
  }
#pragma unroll
  for (int j = 0; j < 4; ++j) {
    r4inv(x[j], x[j+4], x[j+8], x[j+12]);
    if (j) {
      x[j+4]  = cmulc(x[j+4],  wA[j-1][0]);
      x[j+8]  = cmulc(x[j+8],  wA[j-1][1]);
      x[j+12] = cmulc(x[j+12], wA[j-1][2]);
    }
  }
#pragma unroll
  for (int c = 0; c < 4; ++c)
    r4inv(x[4*c], x[4*c+1], x[4*c+2], x[4*c+3]);
#pragma unroll
  for (int m = 0; m < 16; ++m) {
    const int p = 16 * kb + m;
    Z[pass ? SWA(lane, p) : SWA(p, lane)] = x[m];
  }
}

// load Q + iK (bit-reversed rows, digit-reversed col groups, SWA swizzle)
__device__ __forceinline__ void sconv_load(float2* __restrict__ Z,
                                           const u32* __restrict__ Qg,
                                           const u32* __restrict__ Kg,
                                           long base, int tid)
{
  const uint4* Q4 = (const uint4*)(Qg + base);
  const uint4* K4 = (const uint4*)(Kg + base);
#pragma unroll
  for (int i = 0; i < 4; ++i) {
    const int v = tid + 256 * i;
    const uint4 q = Q4[v], k = K4[v];
    const int r = v >> 4, w = v & 15;
    const int R  = REV6(r);
    const int cb = ((w & 3) << 2) | (w >> 2);
    Z[SWA(R, cb)]      = make_float2(unpackf(q.x), unpackf(k.x));
    Z[SWA(R, cb + 16)] = make_float2(unpackf(q.y), unpackf(k.y));
    Z[SWA(R, cb + 32)] = make_float2(unpackf(q.z), unpackf(k.z));
    Z[SWA(R, cb + 48)] = make_float2(unpackf(q.w), unpackf(k.w));
  }
}

__global__ __launch_bounds__(256, 2)
void sconv_kernel(const u32* __restrict__ Qg, const u32* __restrict__ Kg,
                  u32* __restrict__ Sg)
{
  __shared__ float2 ZA[4096];    // channel 2c   (32 KB)
  __shared__ float2 ZB[4096];    // channel 2c+1 (32 KB)
  const int tid  = threadIdx.x;
  const int lane = tid & 63;
  const int kb   = tid >> 6;
  const long base = (long)blockIdx.x * 8192;   // two channels per block

  // register twiddles. wA: compile-time (twt[t] = e^{-2pi i t/64}):
  // {t=4,8,12},{8,16,24},{12,24,36}
  const float2 wA[3][3] = {
    { make_float2( 0.92387953251f, -0.38268343236f),
      make_float2( 0.70710678119f, -0.70710678119f),
      make_float2( 0.38268343236f, -0.92387953251f) },
    { make_float2( 0.70710678119f, -0.70710678119f),
      make_float2( 0.f,            -1.f),
      make_float2(-0.70710678119f, -0.70710678119f) },
    { make_float2( 0.38268343236f, -0.92387953251f),
      make_float2(-0.70710678119f, -0.70710678119f),
      make_float2(-0.92387953251f,  0.38268343236f) } };
  float2 wB[4][3];
#pragma unroll
  for (int q = 0; q < 4; ++q) {
    const float k = (float)(kb + 4 * q);   // k <= 15; 3k <= 45 < 64, no mod
    float sn, cs;
    __sincosf(-2.f * (float)M_PI * (1.f / 64.f) * k,        &sn, &cs); wB[q][0] = make_float2(cs, sn);
    __sincosf(-2.f * (float)M_PI * (1.f / 64.f) * (2.f*k),  &sn, &cs); wB[q][1] = make_float2(cs, sn);
    __sincosf(-2.f * (float)M_PI * (1.f / 64.f) * (3.f*k),  &sn, &cs); wB[q][2] = make_float2(cs, sn);
  }

  sconv_load(ZA, Qg, Kg, base, tid);
  sconv_load(ZB, Qg, Kg, base + 4096, tid);
  __syncthreads();

  // two forward FFTs, stage-interleaved between shared barriers
  for (int pass = 0; pass < 2; ++pass) {
    fused01_fwd(ZA, wA, lane, kb, pass);
    fused01_fwd(ZB, wA, lane, kb, pass);
    __syncthreads();
    stage2_fwd(ZA, wB, lane, kb, pass);
    stage2_fwd(ZB, wB, lane, kb, pass);
    __syncthreads();
  }

  // pair-owned pointwise, combined Hermitian pack:  C = P0 + i*P1 -> ZA
#pragma unroll
  for (int i = 0; i < 9; ++i) {
    const int n = tid + 256 * i;
    if (n < 2112) {                       // rows 0..32
      const int u = n >> 6, vv = n & 63;
      if (!((u == 0 || u == 32) && vv > 32)) {
        const int u2 = (64 - u) & 63, v2 = (64 - vv) & 63;
        const int az = SWA(u, vv), am = SWA(u2, v2);
        const float2 z0 = ZA[az], m0 = ZA[am];
        const float2 z1 = ZB[az], m1 = ZB[am];
        const float dre0 = 0.25f * (z0.x*z0.x - z0.y*z0.y - m0.x*m0.x + m0.y*m0.y);
        const float dim0 = 0.5f  * (z0.x*z0.y + m0.x*m0.y);
        const float dre1 = 0.25f * (z1.x*z1.x - z1.y*z1.y - m1.x*m1.x + m1.y*m1.y);
        const float dim1 = 0.5f  * (z1.x*z1.y + m1.x*m1.y);
        ZA[az] = make_float2(dim0 + dre1, dim1 - dre0);
        ZA[am] = make_float2(dim0 - dre1, dim1 + dre0);
      }
    }
  }
  __syncthreads();

  // one inverse FFT on the combined spectrum
  for (int pass = 0; pass < 2; ++pass) {
    stage2_inv(ZA, wB, lane, kb, pass);
    __syncthreads();
    fused01_inv(ZA, wA, lane, kb, pass);
    __syncthreads();
  }

  // store: Re -> S[2c], Im -> S[2c+1]
  uint4* Sa = (uint4*)(Sg + base);
  uint4* Sb = (uint4*)(Sg + base + 4096);
#pragma unroll
  for (int i = 0; i < 4; ++i) {
    const int v = tid + 256 * i;
    const int y = v >> 4, w = v & 15;
    const int Rr = REV6(y);
    const int cb = ((w & 3) << 2) | (w >> 2);
    const float2 e0 = ZA[SWA(Rr, cb)];
    const float2 e1 = ZA[SWA(Rr, cb + 16)];
    const float2 e2 = ZA[SWA(Rr, cb + 32)];
    const float2 e3 = ZA[SWA(Rr, cb + 48)];
    uint4 o;
    o.x = packf(e0.x * (1.f / 4096.f));
    o.y = packf(e1.x * (1.f / 4096.f));
    o.z = packf(e2.x * (1.f / 4096.f));
    o.w = packf(e3.x * (1.f / 4096.f));
    Sa[v] = o;
    o.x = packf(e0.y * (1.f / 4096.f));
    o.y = packf(e1.y * (1.f / 4096.f));
    o.z = packf(e2.y * (1.f / 4096.f));
    o.w = packf(e3.y * (1.f / 4096.f));
    Sb[v] = o;
  }
}

// ---------------------------------------------------------------------------
// Fused split-K reduce + row softmax; writes PACKED attn weights.
// ---------------------------------------------------------------------------
__global__ __launch_bounds__(256)
void softmax_kernel(const float* __restrict__ Lp, u32* __restrict__ L,
                    const float* __restrict__ alpha)
{
  __shared__ float red[256];
  const int row = blockIdx.x, tid = threadIdx.x;
  const int b = row >> 8, c = row & 255;
  const float sc = 4096.f / alpha[0];
  float acc = 0.f;
#pragma unroll
  for (int s = 0; s < SPLITK; ++s)
    acc += Lp[((long)(b * SPLITK + s) * 65536) + (long)c * 256 + tid];
  const float v = fabsf(acc) * sc;
  red[tid] = v; __syncthreads();
  for (int o = 128; o > 0; o >>= 1) {
    if (tid < o) red[tid] = fmaxf(red[tid], red[tid + o]);
    __syncthreads();
  }
  const float mx = red[0];
  __syncthreads();
  const float e = expf(v - mx);
  red[tid] = e; __syncthreads();
  for (int o = 128; o > 0; o >>= 1) {
    if (tid < o) red[tid] += red[tid + o];
    __syncthreads();
  }
  L[(long)row * 256 + tid] = packf(e / red[0]);
}

// ---------------------------------------------------------------------------
extern "C" void kernel_launch(void* const* d_in, const int* in_sizes, int n_in,
                              void* d_out, int out_size, void* d_ws, size_t ws_size,
                              hipStream_t stream)
{
  const float* x1       = (const float*)d_in[0];
  const float* x2       = (const float*)d_in[1];
  const float* conv_r_w = (const float*)d_in[2];
  const float* conv_r_b = (const float*)d_in[3];
  const float* conv_n_w = (const float*)d_in[4];
  const float* conv_n_b = (const float*)d_in[5];
  const float* mlp_w1   = (const float*)d_in[6];
  const float* mlp_w2   = (const float*)d_in[7];
  const float* pq_w     = (const float*)d_in[8];
  const float* pq_b     = (const float*)d_in[9];
  const float* dq_w     = (const float*)d_in[10];
  const float* dq_b     = (const float*)d_in[11];
  const float* pk_w     = (const float*)d_in[12];
  const float* pk_b     = (const float*)d_in[13];
  const float* dk_w     = (const float*)d_in[14];
  const float* dk_b     = (const float*)d_in[15];
  const float* pv_w     = (const float*)d_in[16];
  const float* pv_b     = (const float*)d_in[17];
  const float* dv_w     = (const float*)d_in[18];
  const float* dv_b     = (const float*)d_in[19];
  const float* out_w    = (const float*)d_in[20];
  const float* out_b    = (const float*)d_in[21];
  const float* alpha    = (const float*)d_in[22];
  const float* lambd    = (const float*)d_in[23];
  const float* beta     = (const float*)d_in[24];

  u32* s = (u32*)d_ws;
  u32* S0 = s;             // FR  -> Q        (packed)
  u32* S1 = s + SLOT;      // FN  -> K        (packed)
  u32* S2 = s + 2 * SLOT;  // Fw  -> mix      (packed, in-place)
  u32* S3 = s + 3 * SLOT;  // Pq  -> Krev     (packed)
  u32* S4 = s + 4 * SLOT;  // Pk  -> V        (packed)
  u32* S5 = s + 5 * SLOT;  // Pv  -> S        (packed)
  float* Lp     = (float*)(s + 6 * SLOT);             // [8][SPLITK][256][256] fp32
  u32*   Lb     = (u32*)(Lp + (long)8 * SPLITK * 65536);  // packed attn weights
  float* pooled = (float*)(Lb + (long)8 * 65536);
  float* attn2  = pooled + 2048;
  u32*   wR     = (u32*)(attn2 + 4096);               // packed weights
  u32*   wN     = wR + 65536;
  u32*   wQ     = wN + 32768;
  u32*   wK     = wQ + 65536;
  u32*   wV     = wK + 65536;
  u32*   wO     = wV + 65536;

  const size_t needed =
      (size_t)(6 * SLOT + (long)8 * SPLITK * 65536 + 8L * 65536 + 2048 + 4096
               + 65536 * 5 + 32768) * 4;
  if (ws_size < needed) return;

  const long ST2 = (long)128 * HW;
  const long STL = (long)256 * 256;

  // pre-split all six weight tensors to packed format in ONE launch
  {
    CvtJob jR{conv_r_w, wR, 16384};
    CvtJob jQ{pq_w,     wQ, 16384};
    CvtJob jK{pk_w,     wK, 16384};
    CvtJob jV{pv_w,     wV, 16384};
    CvtJob jO{out_w,    wO, 16384};
    CvtJob jN{conv_n_w, wN, 8192};
    cvt_kernel<<<dim3(64, 6), 256, 0, stream>>>(jR, jQ, jK, jV, jO, jN);
  }

  // FR = conv_r(x1) + FN = conv_n(x2) fused into ONE launch
  {
    GemmSet gR{wR, (const void*)x1, (void*)S0, conv_r_b, 256, ST};
    GemmSet gN{wN, (const void*)x2, (void*)S1, conv_n_b, 128, ST2};
    gemm_mfma<false, 1><<<dim3(32, 2, 8), 512, 0, stream>>>(gR, gN, gN,
        0L, ST, nullptr, nullptr, nullptr, nullptr, nullptr);
  }

  pool_kernel<<<2048, 256, 0, stream>>>(S0, S1, pooled);
  attn2_kernel<<<8, 256, 0, stream>>>(pooled, mlp_w1, mlp_w2, attn2);
  fw_kernel<<<dim3(4, 256, 8), 256, 0, stream>>>(S0, S1, attn2, S2);

  // Pq/Pk/Pv fused into ONE launch: same B (S2) -> same-XCD L2 sharing
  {
    GemmSet gQ{wQ, (const void*)S2, (void*)S3, pq_b, 256, ST};
    GemmSet gK{wK, (const void*)S2, (void*)S4, pk_b, 256, ST};
    GemmSet gV{wV, (const void*)S2, (void*)S5, pv_b, 256, ST};
    gemm_mfma<true, 1><<<dim3(32, 3, 8), 512, 0, stream>>>(gQ, gK, gV,
        0L, ST, nullptr, nullptr, nullptr, nullptr, nullptr);
  }

  // depthwise 3x3 (packed in/out), THREE jobs in ONE launch
  {
    DwJob jQ{S3, dq_w, dq_b, S0, nullptr};   // Q  -> S0
    DwJob jK{S4, dk_w, dk_b, S1, S3};        // K  -> S1, Krev -> S3
    DwJob jV{S5, dv_w, dv_b, S4, nullptr};   // V  -> S4
    dw_kernel<<<dim3(2048, 3), 256, 0, stream>>>(jQ, jK, jV);
  }

  // S = circconv2(Q, K)  — 2 channels/block, dual-LDS paired Hermitian inverse
  sconv_kernel<<<1024, 256, 0, stream>>>(S0, S1, S5);                // S -> S5

  // attn logits via MFMA split-K, then fused reduce+softmax (packed Lb)
  gemm_logits<<<dim3(2, 2, 64), 256, 0, stream>>>(S0, S3, Lp);
  softmax_kernel<<<2048, 256, 0, stream>>>(Lp, Lb, alpha);

  // cfr = attn_w @ S, fused mix epilogue (packed, in-place into S2)
  {
    GemmSet gM{Lb, (const void*)S5, (void*)S2, nullptr, 256, ST};
    gemm_mfma<true, 2><<<dim3(32, 1, 8), 512, 0, stream>>>(gM, gM, gM,
        STL, ST, S0, S4, S2, lambd, beta);
  }

  // final 1x1 conv -> d_out (fp32 + bias)
  {
    GemmSet gO{wO, (const void*)S2, d_out, out_b, 256, ST};
    gemm_mfma<true, 0><<<dim3(32, 1, 8), 512, 0, stream>>>(gO, gO, gO,
        0L, ST, nullptr, nullptr, nullptr, nullptr, nullptr);
  }
}